// Round 7
// baseline (3397.355 us; speedup 1.0000x reference)
//
#include <hip/hip_runtime.h>
#include <hip/hip_bf16.h>

// ---------- types ----------
typedef __attribute__((ext_vector_type(8))) short short8;
typedef __attribute__((ext_vector_type(4))) float f32x4;
typedef __attribute__((ext_vector_type(4))) int int4v;

#define EMB 128
#define OUT 256
#define NRAD 6
#define NDENSE 3
#define SCAN_NB 256   // blocks in hierarchical scan
#define MLP_REP 8     // internal repeats (idempotent) -> rocprof top-5 visibility
#define GP_REP 24

static __device__ __forceinline__ unsigned short f32_to_bf16(float f) {
    union { float f; unsigned u; } v; v.f = f;
    unsigned r = v.u + 0x7fffu + ((v.u >> 16) & 1u);   // round-nearest-even
    return (unsigned short)(r >> 16);
}
static __device__ __forceinline__ float bf16_to_f32(unsigned short h) {
    union { unsigned u; float f; } v; v.u = ((unsigned)h) << 16;
    return v.f;
}
static __device__ __forceinline__ float silu(float x) {
    return x / (1.f + __expf(-x));
}

// ---------- zero (vectorized) ----------
__global__ void zero_kernel(int4v* __restrict__ p, int n4) {
    int stride = gridDim.x * blockDim.x;
    for (int i = blockIdx.x * blockDim.x + threadIdx.x; i < n4; i += stride)
        p[i] = (int4v){0, 0, 0, 0};
}

// ---------- CSR build ----------
__global__ void hist_kernel(const int* __restrict__ src, int* __restrict__ counts, int E) {
    int stride = gridDim.x * blockDim.x;
    for (int e = blockIdx.x * blockDim.x + threadIdx.x; e < E; e += stride)
        atomicAdd(&counts[src[e]], 1);
}

__global__ __launch_bounds__(256) void scanA_kernel(const int* __restrict__ counts,
                                                    int* __restrict__ bsum, int N, int chunk) {
    __shared__ int red[256];
    int b = blockIdx.x, t = threadIdx.x;
    int idx = b * chunk + t;
    int v = (t < chunk && idx < N) ? counts[idx] : 0;
    red[t] = v;
    __syncthreads();
    for (int d = 128; d > 0; d >>= 1) {
        if (t < d) red[t] += red[t + d];
        __syncthreads();
    }
    if (t == 0) bsum[b] = red[0];
}

__global__ __launch_bounds__(256) void scanB_kernel(int* __restrict__ bsum,
                                                    int* __restrict__ bpre,
                                                    int* __restrict__ offsets, int N) {
    __shared__ int s[256];
    int t = threadIdx.x;
    int v = bsum[t];
    s[t] = v;
    __syncthreads();
    for (int d = 1; d < 256; d <<= 1) {
        int x = (t >= d) ? s[t - d] : 0;
        __syncthreads();
        s[t] += x;
        __syncthreads();
    }
    bpre[t] = s[t] - v;             // exclusive
    if (t == 255) offsets[N] = s[t]; // total == E
}

__global__ __launch_bounds__(256) void scanC_kernel(const int* __restrict__ counts,
                                                    const int* __restrict__ bpre,
                                                    int* __restrict__ offsets, int N, int chunk) {
    __shared__ int s[256];
    int b = blockIdx.x, t = threadIdx.x;
    int idx = b * chunk + t;
    int v = (t < chunk && idx < N) ? counts[idx] : 0;
    s[t] = v;
    __syncthreads();
    for (int d = 1; d < 256; d <<= 1) {
        int x = (t >= d) ? s[t - d] : 0;
        __syncthreads();
        s[t] += x;
        __syncthreads();
    }
    if (t < chunk && idx < N) offsets[idx] = bpre[b] + s[t] - v;
}

__global__ void scatter_kernel(const int* __restrict__ src, const int* __restrict__ offsets,
                               int* __restrict__ counts /*consumed to 0*/,
                               int* __restrict__ perm, int E) {
    int stride = gridDim.x * blockDim.x;
    for (int e = blockIdx.x * blockDim.x + threadIdx.x; e < E; e += stride) {
        int s = src[e];
        int idx = atomicSub(&counts[s], 1) - 1;   // unique slot within node
        perm[offsets[s] + idx] = e;
    }
}

// ---------- weight prep (f32 -> bf16) ----------
__global__ void prep_w_kernel(const float* __restrict__ Wup, const float* __restrict__ Wd,
                              unsigned short* __restrict__ out) {
    const int n1 = OUT * EMB;
    const int n2 = NDENSE * OUT * OUT;
    int stride = gridDim.x * blockDim.x;
    for (int i = blockIdx.x * blockDim.x + threadIdx.x; i < n1 + n2; i += stride)
        out[i] = f32_to_bf16(i < n1 ? Wup[i] : Wd[i - n1]);
}

// ---------- fused edge transform + per-node gather-sum (IDENTICAL to R4) ----------
__global__ __launch_bounds__(256) void edge_accum_kernel(
        const float* __restrict__ m, const float* __restrict__ rbf,
        const int* __restrict__ perm, const int* __restrict__ offsets,
        const float* __restrict__ W_rbf, unsigned* __restrict__ t_pack, int N) {
    const int lane = threadIdx.x & 63;
    const int gw = blockIdx.x * (blockDim.x >> 6) + (threadIdx.x >> 6);
    const int nwaves = gridDim.x * (blockDim.x >> 6);

    const float* wr = W_rbf + lane * 2 * NRAD;
    const float wa0 = wr[0], wa1 = wr[1], wa2 = wr[2], wa3 = wr[3], wa4 = wr[4], wa5 = wr[5];
    const float wb0 = wr[6], wb1 = wr[7], wb2 = wr[8], wb3 = wr[9], wb4 = wr[10], wb5 = wr[11];

    for (int node = gw; node < N; node += nwaves) {
        int beg = offsets[node], end = offsets[node + 1];
        float ax = 0.f, ay = 0.f;
        for (int i = beg; i < end; i += 4) {
            int rem = end - i;
            int i1 = (rem > 1) ? i + 1 : i;
            int i2 = (rem > 2) ? i + 2 : i;
            int i3 = (rem > 3) ? i + 3 : i;
            int e0 = perm[i], e1 = perm[i1], e2 = perm[i2], e3 = perm[i3];
            const float2* rp0 = (const float2*)(rbf + (size_t)e0 * NRAD);
            const float2* rp1 = (const float2*)(rbf + (size_t)e1 * NRAD);
            const float2* rp2 = (const float2*)(rbf + (size_t)e2 * NRAD);
            const float2* rp3 = (const float2*)(rbf + (size_t)e3 * NRAD);
            float2 q00 = rp0[0], q01 = rp0[1], q02 = rp0[2];
            float2 q10 = rp1[0], q11 = rp1[1], q12 = rp1[2];
            float2 q20 = rp2[0], q21 = rp2[1], q22 = rp2[2];
            float2 q30 = rp3[0], q31 = rp3[1], q32 = rp3[2];
            const float2 m0 = *(const float2*)(m + (size_t)e0 * EMB + 2 * lane);
            const float2 m1 = *(const float2*)(m + (size_t)e1 * EMB + 2 * lane);
            const float2 m2 = *(const float2*)(m + (size_t)e2 * EMB + 2 * lane);
            const float2 m3 = *(const float2*)(m + (size_t)e3 * EMB + 2 * lane);
            float g1 = (rem > 1) ? 1.f : 0.f;
            float g2 = (rem > 2) ? 1.f : 0.f;
            float g3 = (rem > 3) ? 1.f : 0.f;
            float pa0 = wa0*q00.x + wa1*q00.y + wa2*q01.x + wa3*q01.y + wa4*q02.x + wa5*q02.y;
            float pb0 = wb0*q00.x + wb1*q00.y + wb2*q01.x + wb3*q01.y + wb4*q02.x + wb5*q02.y;
            float pa1 = (wa0*q10.x + wa1*q10.y + wa2*q11.x + wa3*q11.y + wa4*q12.x + wa5*q12.y) * g1;
            float pb1 = (wb0*q10.x + wb1*q10.y + wb2*q11.x + wb3*q11.y + wb4*q12.x + wb5*q12.y) * g1;
            float pa2 = (wa0*q20.x + wa1*q20.y + wa2*q21.x + wa3*q21.y + wa4*q22.x + wa5*q22.y) * g2;
            float pb2 = (wb0*q20.x + wb1*q20.y + wb2*q21.x + wb3*q21.y + wb4*q22.x + wb5*q22.y) * g2;
            float pa3 = (wa0*q30.x + wa1*q30.y + wa2*q31.x + wa3*q31.y + wa4*q32.x + wa5*q32.y) * g3;
            float pb3 = (wb0*q30.x + wb1*q30.y + wb2*q31.x + wb3*q31.y + wb4*q32.x + wb5*q32.y) * g3;
            ax = fmaf(m0.x, pa0, ax); ay = fmaf(m0.y, pb0, ay);
            ax = fmaf(m1.x, pa1, ax); ay = fmaf(m1.y, pb1, ay);
            ax = fmaf(m2.x, pa2, ax); ay = fmaf(m2.y, pb2, ay);
            ax = fmaf(m3.x, pa3, ax); ay = fmaf(m3.y, pb3, ay);
        }
        unsigned short hx = f32_to_bf16(ax), hy = f32_to_bf16(ay);
        t_pack[(size_t)node * 64 + lane] = (unsigned)hx | ((unsigned)hy << 16);
    }
}

// ---------- fused MLP (internally repeated MLP_REP x, idempotent) ----------
__global__ __launch_bounds__(256) void fused_mlp_kernel(
        const unsigned short* __restrict__ A0,    // [M,128] bf16
        const unsigned short* __restrict__ Wup,   // [256,128] bf16
        const unsigned short* __restrict__ Wd,    // [3,256,256] bf16
        const float* __restrict__ bd,             // [3,256]
        unsigned short* __restrict__ Hout, int M) {
    __shared__ unsigned short smem[4][16 * 256];
    const int w    = threadIdx.x >> 6;
    const int lane = threadIdx.x & 63;
    const int r    = lane & 15;
    const int g    = lane >> 4;          // khalf / row-group
    const int row0 = blockIdx.x * 64 + w * 16;
    char* swc = (char*)&smem[w][0];

#pragma unroll 1
    for (int rep = 0; rep < MLP_REP; ++rep) {
        __syncthreads();   // protect LDS reuse across reps

        f32x4 acc[16];
#pragma unroll
        for (int i = 0; i < 16; ++i) acc[i] = (f32x4){0.f, 0.f, 0.f, 0.f};

        // ---- layer 0: up-projection, K=128, A from global ----
        const int arow = row0 + r;
        const bool rowok = (arow < M);
        const unsigned short* Arow = A0 + (size_t)arow * EMB;
#pragma unroll
        for (int ks = 0; ks < EMB; ks += 32) {
            int ka = ks + g * 8;
            short8 afrag;
            if (rowok) afrag = *(const short8*)(Arow + ka);
            else       afrag = (short8){0,0,0,0,0,0,0,0};
#pragma unroll
            for (int ct = 0; ct < 16; ++ct) {
                int col = ct * 16 + r;
                short8 bfrag = *(const short8*)(Wup + (size_t)col * EMB + ka);
                acc[ct] = __builtin_amdgcn_mfma_f32_16x16x32_bf16(afrag, bfrag, acc[ct], 0, 0, 0);
            }
        }

        // stash layer-0 output into LDS (XOR swizzle)
#pragma unroll
        for (int ct = 0; ct < 16; ++ct) {
            int col = ct * 16 + r;
#pragma unroll
            for (int reg = 0; reg < 4; ++reg) {
                int rw = 4 * g + reg;
                int byte = rw * 512 + col * 2;
                byte ^= (rw & 7) << 4;
                *(unsigned short*)(swc + byte) = f32_to_bf16(acc[ct][reg]);
            }
        }
        __syncthreads();

        // ---- layers 1..3: dense 256x256 + bias + silu ----
        for (int ell = 0; ell < NDENSE; ++ell) {
            const unsigned short* Bl = Wd + (size_t)ell * OUT * OUT;
            const float* bias = bd + ell * OUT;
#pragma unroll
            for (int i = 0; i < 16; ++i) acc[i] = (f32x4){0.f, 0.f, 0.f, 0.f};
#pragma unroll
            for (int ks = 0; ks < 8; ++ks) {
                int byte = r * 512 + ks * 64 + g * 16;
                byte ^= (r & 7) << 4;
                short8 afrag = *(const short8*)(swc + byte);
                int ka = ks * 32 + g * 8;
#pragma unroll
                for (int ct = 0; ct < 16; ++ct) {
                    int col = ct * 16 + r;
                    short8 bfrag = *(const short8*)(Bl + (size_t)col * OUT + ka);
                    acc[ct] = __builtin_amdgcn_mfma_f32_16x16x32_bf16(afrag, bfrag, acc[ct], 0, 0, 0);
                }
            }
            if (ell < NDENSE - 1) {
                __syncthreads();
#pragma unroll
                for (int ct = 0; ct < 16; ++ct) {
                    int col = ct * 16 + r;
                    float b = bias[col];
#pragma unroll
                    for (int reg = 0; reg < 4; ++reg) {
                        int rw = 4 * g + reg;
                        int byte = rw * 512 + col * 2;
                        byte ^= (rw & 7) << 4;
                        *(unsigned short*)(swc + byte) = f32_to_bf16(silu(acc[ct][reg] + b));
                    }
                }
                __syncthreads();
            } else {
                const int orow_base = row0 + g * 4;
#pragma unroll
                for (int ct = 0; ct < 16; ++ct) {
                    int col = ct * 16 + r;
                    float b = bias[col];
#pragma unroll
                    for (int reg = 0; reg < 4; ++reg) {
                        int orow = orow_base + reg;
                        if (orow < M)
                            Hout[(size_t)orow * OUT + col] = f32_to_bf16(silu(acc[ct][reg] + b));
                    }
                }
            }
        }
    }
}

// ---------- per-graph sum (internally repeated GP_REP x, idempotent) ----------
__global__ __launch_bounds__(256) void graph_partial_kernel(
        const unsigned short* __restrict__ h, const int* __restrict__ gids,
        float* __restrict__ partial, int M) {
#pragma unroll 1
    for (int rep = 0; rep < GP_REP; ++rep) {
        int gph = blockIdx.x, s = blockIdx.y;
        int c = threadIdx.x;
        int lo = 0, hi = M;
        while (lo < hi) { int mid = (lo + hi) >> 1; if (gids[mid] < gph) lo = mid + 1; else hi = mid; }
        int lo2 = lo, hi2 = M;
        while (lo2 < hi2) { int mid = (lo2 + hi2) >> 1; if (gids[mid] < gph + 1) lo2 = mid + 1; else hi2 = mid; }
        int len = lo2 - lo;
        int q = (len + 3) >> 2;
        int b0 = lo + s * q;
        int b1 = b0 + q; if (b1 > lo2) b1 = lo2;
        float a0 = 0.f, a1 = 0.f;
        int n = b0;
        for (; n + 1 < b1; n += 2) {
            a0 += bf16_to_f32(h[(size_t)n * OUT + c]);
            a1 += bf16_to_f32(h[(size_t)(n + 1) * OUT + c]);
        }
        for (; n < b1; ++n) a0 += bf16_to_f32(h[(size_t)n * OUT + c]);
        partial[((size_t)gph * 4 + s) * OUT + c] = a0 + a1;
    }
}

__global__ __launch_bounds__(256) void graph_final_kernel(
        const float* __restrict__ partial, float* __restrict__ out) {
    int gph = blockIdx.x, c = threadIdx.x;
    const float* p = partial + (size_t)gph * 4 * OUT + c;
    out[(size_t)gph * OUT + c] = (p[0] + p[OUT]) + (p[2 * OUT] + p[3 * OUT]);
}

// ---------- host ----------
extern "C" void kernel_launch(void* const* d_in, const int* in_sizes, int n_in,
                              void* d_out, int out_size, void* d_ws, size_t ws_size,
                              hipStream_t stream) {
    const float* m         = (const float*)d_in[0];
    const float* rbf       = (const float*)d_in[1];
    const int*   src       = (const int*)d_in[2];
    const int*   gids      = (const int*)d_in[3];
    const float* W_rbf     = (const float*)d_in[4];
    const float* W_up      = (const float*)d_in[5];
    const float* W_dense   = (const float*)d_in[6];
    const float* b_dense   = (const float*)d_in[7];
    float* out = (float*)d_out;

    const int E = in_sizes[2];
    const int N = in_sizes[3];
    const int G = out_size / OUT;

    size_t off = 0;
    auto alloc = [&](size_t bytes) -> void* {
        void* p = (char*)d_ws + off;
        off += (bytes + 255) & ~(size_t)255;
        return p;
    };
    int* counts  = (int*)alloc((size_t)N * 4);
    int* offsets = (int*)alloc(((size_t)N + 1) * 4);
    int* perm    = (int*)alloc((size_t)E * 4);
    int* bsum    = (int*)alloc(SCAN_NB * 4);
    int* bpre    = (int*)alloc(SCAN_NB * 4);
    unsigned short* t_bf = (unsigned short*)alloc((size_t)N * EMB * 2);
    unsigned short* hbuf = (unsigned short*)alloc((size_t)N * OUT * 2);
    float* partial       = (float*)alloc((size_t)G * 4 * OUT * 4);
    unsigned short* Wbf  = (unsigned short*)alloc((size_t)(OUT * EMB + NDENSE * OUT * OUT) * 2);
    unsigned short* Wup_bf = Wbf;
    unsigned short* Wd_bf  = Wbf + OUT * EMB;

    const int chunk = (N + SCAN_NB - 1) / SCAN_NB;

    // CSR build x3 (sequence idempotent) -> CSR cost by subtraction
    for (int r = 0; r < 3; ++r) {
        zero_kernel<<<64, 256, 0, stream>>>((int4v*)counts, N / 4);
        hist_kernel<<<1024, 256, 0, stream>>>(src, counts, E);
        scanA_kernel<<<SCAN_NB, 256, 0, stream>>>(counts, bsum, N, chunk);
        scanB_kernel<<<1, 256, 0, stream>>>(bsum, bpre, offsets, N);
        scanC_kernel<<<SCAN_NB, 256, 0, stream>>>(counts, bpre, offsets, N, chunk);
        scatter_kernel<<<1024, 256, 0, stream>>>(src, offsets, counts, perm, E);
    }

    // weights -> bf16
    prep_w_kernel<<<256, 256, 0, stream>>>(W_up, W_dense, Wbf);

    // edge transform + node gather (x1, known 282us)
    edge_accum_kernel<<<2048, 256, 0, stream>>>(m, rbf, perm, offsets, W_rbf,
                                                (unsigned*)t_bf, N);

    // fused up-proj + 3x dense+silu (x8 internal -> top-5 visible w/ counters)
    fused_mlp_kernel<<<(N + 63) / 64, 256, 0, stream>>>(t_bf, Wup_bf, Wd_bf, b_dense, hbuf, N);

    // per-graph readout (x24 internal -> top-5 visible w/ counters)
    graph_partial_kernel<<<dim3(G, 4), 256, 0, stream>>>(hbuf, gids, partial, N);
    graph_final_kernel<<<G, 256, 0, stream>>>(partial, out);
}

// Round 8
// 575.677 us; speedup vs baseline: 5.9015x; 5.9015x over previous
//
#include <hip/hip_runtime.h>
#include <hip/hip_bf16.h>

// ---------- types ----------
typedef __attribute__((ext_vector_type(8))) short short8;
typedef __attribute__((ext_vector_type(4))) float f32x4;
typedef __attribute__((ext_vector_type(4))) int int4v;

#define EMB 128
#define OUT 256
#define NRAD 6
#define NDENSE 3
#define SCAN_NB 256

static __device__ __forceinline__ unsigned short f32_to_bf16(float f) {
    union { float f; unsigned u; } v; v.f = f;
    unsigned r = v.u + 0x7fffu + ((v.u >> 16) & 1u);   // round-nearest-even
    return (unsigned short)(r >> 16);
}
static __device__ __forceinline__ float bf16_to_f32(unsigned short h) {
    union { unsigned u; float f; } v; v.u = ((unsigned)h) << 16;
    return v.f;
}
static __device__ __forceinline__ float silu(float x) {
    return x / (1.f + __expf(-x));
}
static __device__ __forceinline__ void gload_lds16(const void* gp, void* lp) {
    __builtin_amdgcn_global_load_lds(
        (const __attribute__((address_space(1))) void*)gp,
        (__attribute__((address_space(3))) void*)lp, 16, 0, 0);
}

// ---------- zero ----------
__global__ void zero_kernel(int4v* __restrict__ p, int n4) {
    int stride = gridDim.x * blockDim.x;
    for (int i = blockIdx.x * blockDim.x + threadIdx.x; i < n4; i += stride)
        p[i] = (int4v){0, 0, 0, 0};
}

// ---------- CSR build: hist saves per-edge slot -> scatter is atomic-free ----------
__global__ void hist_kernel(const int* __restrict__ src, int* __restrict__ counts,
                            int* __restrict__ idx, int E) {
    int stride = gridDim.x * blockDim.x;
    for (int e = blockIdx.x * blockDim.x + threadIdx.x; e < E; e += stride)
        idx[e] = atomicAdd(&counts[src[e]], 1);
}

__global__ __launch_bounds__(256) void scanA_kernel(const int* __restrict__ counts,
                                                    int* __restrict__ bsum, int N, int chunk) {
    __shared__ int red[256];
    int b = blockIdx.x, t = threadIdx.x;
    int idx = b * chunk + t;
    int v = (t < chunk && idx < N) ? counts[idx] : 0;
    red[t] = v;
    __syncthreads();
    for (int d = 128; d > 0; d >>= 1) {
        if (t < d) red[t] += red[t + d];
        __syncthreads();
    }
    if (t == 0) bsum[b] = red[0];
}

__global__ __launch_bounds__(256) void scanB_kernel(int* __restrict__ bsum,
                                                    int* __restrict__ bpre,
                                                    int* __restrict__ offsets, int N) {
    __shared__ int s[256];
    int t = threadIdx.x;
    int v = bsum[t];
    s[t] = v;
    __syncthreads();
    for (int d = 1; d < 256; d <<= 1) {
        int x = (t >= d) ? s[t - d] : 0;
        __syncthreads();
        s[t] += x;
        __syncthreads();
    }
    bpre[t] = s[t] - v;
    if (t == 255) offsets[N] = s[t];
}

__global__ __launch_bounds__(256) void scanC_kernel(const int* __restrict__ counts,
                                                    const int* __restrict__ bpre,
                                                    int* __restrict__ offsets, int N, int chunk) {
    __shared__ int s[256];
    int b = blockIdx.x, t = threadIdx.x;
    int idx = b * chunk + t;
    int v = (t < chunk && idx < N) ? counts[idx] : 0;
    s[t] = v;
    __syncthreads();
    for (int d = 1; d < 256; d <<= 1) {
        int x = (t >= d) ? s[t - d] : 0;
        __syncthreads();
        s[t] += x;
        __syncthreads();
    }
    if (t < chunk && idx < N) offsets[idx] = bpre[b] + s[t] - v;
}

__global__ void scatter_kernel(const int* __restrict__ src, const int* __restrict__ offsets,
                               const int* __restrict__ idx, int* __restrict__ perm, int E) {
    int stride = gridDim.x * blockDim.x;
    for (int e = blockIdx.x * blockDim.x + threadIdx.x; e < E; e += stride) {
        int s = src[e];
        perm[offsets[s] + idx[e]] = e;   // slot reserved in hist; no atomic
    }
}

// ---------- weight prep ----------
__global__ void prep_w_kernel(const float* __restrict__ Wup, const float* __restrict__ Wd,
                              unsigned short* __restrict__ out) {
    const int n1 = OUT * EMB;
    const int n2 = NDENSE * OUT * OUT;
    int stride = gridDim.x * blockDim.x;
    for (int i = blockIdx.x * blockDim.x + threadIdx.x; i < n1 + n2; i += stride)
        out[i] = f32_to_bf16(i < n1 ? Wup[i] : Wd[i - n1]);
}

// ---------- fused edge transform + per-node gather-sum (IDENTICAL to R4, 282us) ----------
__global__ __launch_bounds__(256) void edge_accum_kernel(
        const float* __restrict__ m, const float* __restrict__ rbf,
        const int* __restrict__ perm, const int* __restrict__ offsets,
        const float* __restrict__ W_rbf, unsigned* __restrict__ t_pack, int N) {
    const int lane = threadIdx.x & 63;
    const int gw = blockIdx.x * (blockDim.x >> 6) + (threadIdx.x >> 6);
    const int nwaves = gridDim.x * (blockDim.x >> 6);

    const float* wr = W_rbf + lane * 2 * NRAD;
    const float wa0 = wr[0], wa1 = wr[1], wa2 = wr[2], wa3 = wr[3], wa4 = wr[4], wa5 = wr[5];
    const float wb0 = wr[6], wb1 = wr[7], wb2 = wr[8], wb3 = wr[9], wb4 = wr[10], wb5 = wr[11];

    for (int node = gw; node < N; node += nwaves) {
        int beg = offsets[node], end = offsets[node + 1];
        float ax = 0.f, ay = 0.f;
        for (int i = beg; i < end; i += 4) {
            int rem = end - i;
            int i1 = (rem > 1) ? i + 1 : i;
            int i2 = (rem > 2) ? i + 2 : i;
            int i3 = (rem > 3) ? i + 3 : i;
            int e0 = perm[i], e1 = perm[i1], e2 = perm[i2], e3 = perm[i3];
            const float2* rp0 = (const float2*)(rbf + (size_t)e0 * NRAD);
            const float2* rp1 = (const float2*)(rbf + (size_t)e1 * NRAD);
            const float2* rp2 = (const float2*)(rbf + (size_t)e2 * NRAD);
            const float2* rp3 = (const float2*)(rbf + (size_t)e3 * NRAD);
            float2 q00 = rp0[0], q01 = rp0[1], q02 = rp0[2];
            float2 q10 = rp1[0], q11 = rp1[1], q12 = rp1[2];
            float2 q20 = rp2[0], q21 = rp2[1], q22 = rp2[2];
            float2 q30 = rp3[0], q31 = rp3[1], q32 = rp3[2];
            const float2 m0 = *(const float2*)(m + (size_t)e0 * EMB + 2 * lane);
            const float2 m1 = *(const float2*)(m + (size_t)e1 * EMB + 2 * lane);
            const float2 m2 = *(const float2*)(m + (size_t)e2 * EMB + 2 * lane);
            const float2 m3 = *(const float2*)(m + (size_t)e3 * EMB + 2 * lane);
            float g1 = (rem > 1) ? 1.f : 0.f;
            float g2 = (rem > 2) ? 1.f : 0.f;
            float g3 = (rem > 3) ? 1.f : 0.f;
            float pa0 = wa0*q00.x + wa1*q00.y + wa2*q01.x + wa3*q01.y + wa4*q02.x + wa5*q02.y;
            float pb0 = wb0*q00.x + wb1*q00.y + wb2*q01.x + wb3*q01.y + wb4*q02.x + wb5*q02.y;
            float pa1 = (wa0*q10.x + wa1*q10.y + wa2*q11.x + wa3*q11.y + wa4*q12.x + wa5*q12.y) * g1;
            float pb1 = (wb0*q10.x + wb1*q10.y + wb2*q11.x + wb3*q11.y + wb4*q12.x + wb5*q12.y) * g1;
            float pa2 = (wa0*q20.x + wa1*q20.y + wa2*q21.x + wa3*q21.y + wa4*q22.x + wa5*q22.y) * g2;
            float pb2 = (wb0*q20.x + wb1*q20.y + wb2*q21.x + wb3*q21.y + wb4*q22.x + wb5*q22.y) * g2;
            float pa3 = (wa0*q30.x + wa1*q30.y + wa2*q31.x + wa3*q31.y + wa4*q32.x + wa5*q32.y) * g3;
            float pb3 = (wb0*q30.x + wb1*q30.y + wb2*q31.x + wb3*q31.y + wb4*q32.x + wb5*q32.y) * g3;
            ax = fmaf(m0.x, pa0, ax); ay = fmaf(m0.y, pb0, ay);
            ax = fmaf(m1.x, pa1, ax); ay = fmaf(m1.y, pb1, ay);
            ax = fmaf(m2.x, pa2, ax); ay = fmaf(m2.y, pb2, ay);
            ax = fmaf(m3.x, pa3, ax); ay = fmaf(m3.y, pb3, ay);
        }
        unsigned short hx = f32_to_bf16(ax), hy = f32_to_bf16(ay);
        t_pack[(size_t)node * 64 + lane] = (unsigned)hx | ((unsigned)hy << 16);
    }
}

// ---------- GEMM (m97-style): C[M,256] = act(A[M,K] @ W^T + bias) ----------
// 128x128 block tile, 4 waves, wave = 64x64 (acc[4][4]); A,W staged to LDS via
// global_load_lds w=16 with XOR swizzle (pre-swizzled global source + swizzled
// ds_read). 8 ds_read_b128 per 16 MFMA.
template<int K, int ACT>
__global__ __launch_bounds__(256) void gemm2_kernel(
        const unsigned short* __restrict__ A, const unsigned short* __restrict__ W,
        const float* __restrict__ bias, unsigned short* __restrict__ C, int M) {
    __shared__ char lds[32768];          // As[128][128B] + Ws[128][128B]
    char* As = lds;
    char* Ws = lds + 16384;

    const int w    = threadIdx.x >> 6;
    const int lane = threadIdx.x & 63;
    const int r    = lane & 15;
    const int g    = lane >> 4;
    const int wr   = w >> 1;             // 0..1 row half
    const int wc   = w & 1;              // 0..1 col half
    const int row0 = blockIdx.x * 128;
    const int col0 = blockIdx.y * 128;

    f32x4 acc[4][4];
#pragma unroll
    for (int i = 0; i < 4; ++i)
#pragma unroll
        for (int j = 0; j < 4; ++j) acc[i][j] = (f32x4){0.f, 0.f, 0.f, 0.f};

    const int lrow = (lane >> 3);        // 0..7 within 8-row slot group
    const int cdst = (lane & 7) * 16;    // byte within 128B row

    for (int kc = 0; kc < K; kc += 64) {
        if (kc) __syncthreads();         // readers done with LDS
        // stage A tile [128 rows][64 k] and W tile [128 cols][64 k]
#pragma unroll
        for (int it = 0; it < 4; ++it) {
            int slot = it * 4 + w;       // 0..15 -> 8 rows each
            int row  = slot * 8 + lrow;  // 0..127
            int csrc = cdst ^ ((row & 7) << 4);
            int ga   = row0 + row; if (ga >= M) ga = M - 1;
            gload_lds16((const char*)A + ((size_t)ga * K + kc) * 2 + csrc,
                        As + slot * 1024);
            int gw_  = col0 + row;       // always < 256
            gload_lds16((const char*)W + ((size_t)gw_ * K + kc) * 2 + csrc,
                        Ws + slot * 1024);
        }
        asm volatile("s_waitcnt vmcnt(0)" ::: "memory");
        __syncthreads();

#pragma unroll
        for (int ks = 0; ks < 2; ++ks) {
            short8 af[4], bf[4];
#pragma unroll
            for (int mi = 0; mi < 4; ++mi) {
                int row = wr * 64 + mi * 16 + r;
                int byte = row * 128 + ks * 64 + g * 16;
                byte ^= (r & 7) << 4;    // row&7 == r&7
                af[mi] = *(const short8*)(As + byte);
            }
#pragma unroll
            for (int nj = 0; nj < 4; ++nj) {
                int col = wc * 64 + nj * 16 + r;
                int byte = col * 128 + ks * 64 + g * 16;
                byte ^= (r & 7) << 4;
                bf[nj] = *(const short8*)(Ws + byte);
            }
#pragma unroll
            for (int mi = 0; mi < 4; ++mi)
#pragma unroll
                for (int nj = 0; nj < 4; ++nj)
                    acc[mi][nj] = __builtin_amdgcn_mfma_f32_16x16x32_bf16(
                        af[mi], bf[nj], acc[mi][nj], 0, 0, 0);
        }
    }

    // epilogue: D layout col=lane&15, row=(lane>>4)*4+reg
#pragma unroll
    for (int nj = 0; nj < 4; ++nj) {
        int gcol = col0 + wc * 64 + nj * 16 + r;
        float b = bias ? bias[gcol] : 0.f;
#pragma unroll
        for (int mi = 0; mi < 4; ++mi) {
#pragma unroll
            for (int q = 0; q < 4; ++q) {
                int grow = row0 + wr * 64 + mi * 16 + g * 4 + q;
                if (grow < M) {
                    float x = acc[mi][nj][q] + b;
                    if (ACT) x = silu(x);
                    C[(size_t)grow * OUT + gcol] = f32_to_bf16(x);
                }
            }
        }
    }
}

// ---------- per-graph sum: 4 deterministic partials + combine ----------
__global__ __launch_bounds__(256) void graph_partial_kernel(
        const unsigned short* __restrict__ h, const int* __restrict__ gids,
        float* __restrict__ partial, int M) {
    int gph = blockIdx.x, s = blockIdx.y;
    int c = threadIdx.x;
    int lo = 0, hi = M;
    while (lo < hi) { int mid = (lo + hi) >> 1; if (gids[mid] < gph) lo = mid + 1; else hi = mid; }
    int lo2 = lo, hi2 = M;
    while (lo2 < hi2) { int mid = (lo2 + hi2) >> 1; if (gids[mid] < gph + 1) lo2 = mid + 1; else hi2 = mid; }
    int len = lo2 - lo;
    int q = (len + 3) >> 2;
    int b0 = lo + s * q;
    int b1 = b0 + q; if (b1 > lo2) b1 = lo2;
    float a0 = 0.f, a1 = 0.f;
    int n = b0;
    for (; n + 1 < b1; n += 2) {
        a0 += bf16_to_f32(h[(size_t)n * OUT + c]);
        a1 += bf16_to_f32(h[(size_t)(n + 1) * OUT + c]);
    }
    for (; n < b1; ++n) a0 += bf16_to_f32(h[(size_t)n * OUT + c]);
    partial[((size_t)gph * 4 + s) * OUT + c] = a0 + a1;
}

__global__ __launch_bounds__(256) void graph_final_kernel(
        const float* __restrict__ partial, float* __restrict__ out) {
    int gph = blockIdx.x, c = threadIdx.x;
    const float* p = partial + (size_t)gph * 4 * OUT + c;
    out[(size_t)gph * OUT + c] = (p[0] + p[OUT]) + (p[2 * OUT] + p[3 * OUT]);
}

// ---------- host ----------
extern "C" void kernel_launch(void* const* d_in, const int* in_sizes, int n_in,
                              void* d_out, int out_size, void* d_ws, size_t ws_size,
                              hipStream_t stream) {
    const float* m         = (const float*)d_in[0];
    const float* rbf       = (const float*)d_in[1];
    const int*   src       = (const int*)d_in[2];
    const int*   gids      = (const int*)d_in[3];
    const float* W_rbf     = (const float*)d_in[4];
    const float* W_up      = (const float*)d_in[5];
    const float* W_dense   = (const float*)d_in[6];
    const float* b_dense   = (const float*)d_in[7];
    float* out = (float*)d_out;

    const int E = in_sizes[2];
    const int N = in_sizes[3];
    const int G = out_size / OUT;

    size_t off = 0;
    auto alloc = [&](size_t bytes) -> void* {
        void* p = (char*)d_ws + off;
        off += (bytes + 255) & ~(size_t)255;
        return p;
    };
    int* counts  = (int*)alloc((size_t)N * 4);
    int* offsets = (int*)alloc(((size_t)N + 1) * 4);
    int* eidx    = (int*)alloc((size_t)E * 4);
    int* perm    = (int*)alloc((size_t)E * 4);
    int* bsum    = (int*)alloc(SCAN_NB * 4);
    int* bpre    = (int*)alloc(SCAN_NB * 4);
    unsigned short* t_bf = (unsigned short*)alloc((size_t)N * EMB * 2);
    unsigned short* h0   = (unsigned short*)alloc((size_t)N * OUT * 2);
    unsigned short* h1   = (unsigned short*)alloc((size_t)N * OUT * 2);
    float* partial       = (float*)alloc((size_t)G * 4 * OUT * 4);
    unsigned short* Wbf  = (unsigned short*)alloc((size_t)(OUT * EMB + NDENSE * OUT * OUT) * 2);
    unsigned short* Wup_bf = Wbf;
    unsigned short* Wd_bf  = Wbf + OUT * EMB;

    const int chunk = (N + SCAN_NB - 1) / SCAN_NB;

    // CSR build (1 atomic pass)
    zero_kernel<<<64, 256, 0, stream>>>((int4v*)counts, N / 4);
    hist_kernel<<<1024, 256, 0, stream>>>(src, counts, eidx, E);
    scanA_kernel<<<SCAN_NB, 256, 0, stream>>>(counts, bsum, N, chunk);
    scanB_kernel<<<1, 256, 0, stream>>>(bsum, bpre, offsets, N);
    scanC_kernel<<<SCAN_NB, 256, 0, stream>>>(counts, bpre, offsets, N, chunk);
    scatter_kernel<<<1024, 256, 0, stream>>>(src, offsets, eidx, perm, E);

    // weights -> bf16
    prep_w_kernel<<<256, 256, 0, stream>>>(W_up, W_dense, Wbf);

    // edge transform + node gather
    edge_accum_kernel<<<2048, 256, 0, stream>>>(m, rbf, perm, offsets, W_rbf,
                                                (unsigned*)t_bf, N);

    // MLP as 4 proper GEMMs (128x128 tile, LDS-staged, 4x4 outer product)
    dim3 ggrid((N + 127) / 128, 2);
    gemm2_kernel<EMB, 0><<<ggrid, 256, 0, stream>>>(t_bf, Wup_bf, nullptr, h0, N);
    gemm2_kernel<OUT, 1><<<ggrid, 256, 0, stream>>>(h0, Wd_bf + 0 * OUT * OUT, b_dense + 0 * OUT, h1, N);
    gemm2_kernel<OUT, 1><<<ggrid, 256, 0, stream>>>(h1, Wd_bf + 1 * OUT * OUT, b_dense + 1 * OUT, h0, N);
    gemm2_kernel<OUT, 1><<<ggrid, 256, 0, stream>>>(h0, Wd_bf + 2 * OUT * OUT, b_dense + 2 * OUT, h1, N);

    // per-graph readout
    graph_partial_kernel<<<dim3(G, 4), 256, 0, stream>>>(h1, gids, partial, N);
    graph_final_kernel<<<G, 256, 0, stream>>>(partial, out);
}

// Round 9
// 520.499 us; speedup vs baseline: 6.5271x; 1.1060x over previous
//
#include <hip/hip_runtime.h>
#include <hip/hip_bf16.h>

// ---------- types ----------
typedef __attribute__((ext_vector_type(8))) short short8;
typedef __attribute__((ext_vector_type(4))) float f32x4;
typedef __attribute__((ext_vector_type(4))) int int4v;

#define EMB 128
#define OUT 256
#define NRAD 6
#define NDENSE 3
#define SCAN_NB 256

static __device__ __forceinline__ unsigned short f32_to_bf16(float f) {
    union { float f; unsigned u; } v; v.f = f;
    unsigned r = v.u + 0x7fffu + ((v.u >> 16) & 1u);   // round-nearest-even
    return (unsigned short)(r >> 16);
}
static __device__ __forceinline__ float bf16_to_f32(unsigned short h) {
    union { unsigned u; float f; } v; v.u = ((unsigned)h) << 16;
    return v.f;
}
static __device__ __forceinline__ float silu(float x) {
    return x / (1.f + __expf(-x));
}
static __device__ __forceinline__ void gload_lds16(const void* gp, void* lp) {
    __builtin_amdgcn_global_load_lds(
        (const __attribute__((address_space(1))) void*)gp,
        (__attribute__((address_space(3))) void*)lp, 16, 0, 0);
}

// ---------- K0: init (zero counts + convert weights) ----------
__global__ __launch_bounds__(256) void init_kernel(
        int* __restrict__ counts, const float* __restrict__ Wup,
        const float* __restrict__ Wd, unsigned short* __restrict__ Wbf, int N) {
    int i = blockIdx.x * blockDim.x + threadIdx.x;
    int stride = gridDim.x * blockDim.x;
    for (int j = i; j < N; j += stride) counts[j] = 0;
    const int n1 = OUT * EMB, n2 = NDENSE * OUT * OUT;
    for (int j = i; j < n1 + n2; j += stride)
        Wbf[j] = f32_to_bf16(j < n1 ? Wup[j] : Wd[j - n1]);
}

// ---------- CSR build: hist saves per-edge slot -> scatter is atomic-free ----------
__global__ void hist_kernel(const int* __restrict__ src, int* __restrict__ counts,
                            int* __restrict__ idx, int E) {
    int stride = gridDim.x * blockDim.x;
    for (int e = blockIdx.x * blockDim.x + threadIdx.x; e < E; e += stride)
        idx[e] = atomicAdd(&counts[src[e]], 1);
}

__global__ __launch_bounds__(256) void scanA_kernel(const int* __restrict__ counts,
                                                    int* __restrict__ bsum, int N, int chunk) {
    __shared__ int red[256];
    int b = blockIdx.x, t = threadIdx.x;
    int idx = b * chunk + t;
    int v = (t < chunk && idx < N) ? counts[idx] : 0;
    red[t] = v;
    __syncthreads();
    for (int d = 128; d > 0; d >>= 1) {
        if (t < d) red[t] += red[t + d];
        __syncthreads();
    }
    if (t == 0) bsum[b] = red[0];
}

__global__ __launch_bounds__(256) void scanB_kernel(int* __restrict__ bsum,
                                                    int* __restrict__ bpre,
                                                    int* __restrict__ offsets, int N) {
    __shared__ int s[256];
    int t = threadIdx.x;
    int v = bsum[t];
    s[t] = v;
    __syncthreads();
    for (int d = 1; d < 256; d <<= 1) {
        int x = (t >= d) ? s[t - d] : 0;
        __syncthreads();
        s[t] += x;
        __syncthreads();
    }
    bpre[t] = s[t] - v;
    if (t == 255) offsets[N] = s[t];
}

__global__ __launch_bounds__(256) void scanC_kernel(const int* __restrict__ counts,
                                                    const int* __restrict__ bpre,
                                                    int* __restrict__ offsets, int N, int chunk) {
    __shared__ int s[256];
    int b = blockIdx.x, t = threadIdx.x;
    int idx = b * chunk + t;
    int v = (t < chunk && idx < N) ? counts[idx] : 0;
    s[t] = v;
    __syncthreads();
    for (int d = 1; d < 256; d <<= 1) {
        int x = (t >= d) ? s[t - d] : 0;
        __syncthreads();
        s[t] += x;
        __syncthreads();
    }
    if (t < chunk && idx < N) offsets[idx] = bpre[b] + s[t] - v;
}

__global__ void scatter_kernel(const int* __restrict__ src, const int* __restrict__ offsets,
                               const int* __restrict__ idx, int* __restrict__ perm, int E) {
    int stride = gridDim.x * blockDim.x;
    for (int e = blockIdx.x * blockDim.x + threadIdx.x; e < E; e += stride) {
        int s = src[e];
        perm[offsets[s] + idx[e]] = e;   // slot reserved in hist; no atomic
    }
}

// ---------- edge transform + per-node gather-sum v2 ----------
// 32 lanes per edge row: lane (c = lane&31) owns cols 4c..4c+3 (float4 m-load);
// h = lane>>5 picks edge-of-pair -> each wave instruction covers TWO 512B rows.
// 8-edge chunks, perm software-pipelined one chunk ahead.
__global__ __launch_bounds__(256) void edge_accum_kernel(
        const float* __restrict__ m, const float* __restrict__ rbf,
        const int* __restrict__ perm, const int* __restrict__ offsets,
        const float* __restrict__ W_rbf, uint2* __restrict__ t_pack, int N) {
    const int lane = threadIdx.x & 63;
    const int h = lane >> 5;             // edge slot within pair
    const int c = lane & 31;             // column quarter (cols 4c..4c+3)
    const int gw = blockIdx.x * (blockDim.x >> 6) + (threadIdx.x >> 6);
    const int nwaves = gridDim.x * (blockDim.x >> 6);

    // W_rbf rows for cols 4c..4c+3 (24 floats)
    float wk[4][6];
#pragma unroll
    for (int k = 0; k < 4; ++k)
#pragma unroll
        for (int j = 0; j < 6; ++j) wk[k][j] = W_rbf[(4 * c + k) * NRAD + j];

    for (int node = gw; node < N; node += nwaves) {
        const int beg = offsets[node], end = offsets[node + 1];
        float a0 = 0.f, a1 = 0.f, a2 = 0.f, a3 = 0.f;
        int pe = 0;
        if (beg < end) {
            int pi = beg + (lane & 7); if (pi > end - 1) pi = end - 1;
            pe = perm[pi];
        }
        for (int cb = beg; cb < end; cb += 8) {
            int pe_next = 0;
            if (cb + 8 < end) {
                int pi = cb + 8 + (lane & 7); if (pi > end - 1) pi = end - 1;
                pe_next = perm[pi];
            }
#pragma unroll
            for (int p = 0; p < 4; ++p) {
                int e = __shfl(pe, 2 * p + h);
                const float2* rp = (const float2*)(rbf + (size_t)e * NRAD);
                float2 r0 = rp[0], r1 = rp[1], r2 = rp[2];
                float4 mv = *(const float4*)(m + (size_t)e * EMB + 4 * c);
                float g = (cb + 2 * p + h < end) ? 1.f : 0.f;
                float p0 = (wk[0][0]*r0.x + wk[0][1]*r0.y + wk[0][2]*r1.x
                          + wk[0][3]*r1.y + wk[0][4]*r2.x + wk[0][5]*r2.y) * g;
                float p1 = (wk[1][0]*r0.x + wk[1][1]*r0.y + wk[1][2]*r1.x
                          + wk[1][3]*r1.y + wk[1][4]*r2.x + wk[1][5]*r2.y) * g;
                float p2 = (wk[2][0]*r0.x + wk[2][1]*r0.y + wk[2][2]*r1.x
                          + wk[2][3]*r1.y + wk[2][4]*r2.x + wk[2][5]*r2.y) * g;
                float p3 = (wk[3][0]*r0.x + wk[3][1]*r0.y + wk[3][2]*r1.x
                          + wk[3][3]*r1.y + wk[3][4]*r2.x + wk[3][5]*r2.y) * g;
                a0 = fmaf(mv.x, p0, a0);
                a1 = fmaf(mv.y, p1, a1);
                a2 = fmaf(mv.z, p2, a2);
                a3 = fmaf(mv.w, p3, a3);
            }
            pe = pe_next;
        }
        // combine the two edge-halves
        a0 += __shfl_xor(a0, 32);
        a1 += __shfl_xor(a1, 32);
        a2 += __shfl_xor(a2, 32);
        a3 += __shfl_xor(a3, 32);
        if (h == 0) {
            uint2 pk;
            pk.x = (unsigned)f32_to_bf16(a0) | ((unsigned)f32_to_bf16(a1) << 16);
            pk.y = (unsigned)f32_to_bf16(a2) | ((unsigned)f32_to_bf16(a3) << 16);
            t_pack[(size_t)node * 32 + c] = pk;
        }
    }
}

// ---------- GEMM (m97-style): C[M,256] = act(A[M,K] @ W^T + bias) ----------
template<int K, int ACT>
__global__ __launch_bounds__(256) void gemm2_kernel(
        const unsigned short* __restrict__ A, const unsigned short* __restrict__ W,
        const float* __restrict__ bias, unsigned short* __restrict__ C, int M) {
    __shared__ char lds[32768];          // As[128][128B] + Ws[128][128B]
    char* As = lds;
    char* Ws = lds + 16384;

    const int w    = threadIdx.x >> 6;
    const int lane = threadIdx.x & 63;
    const int r    = lane & 15;
    const int g    = lane >> 4;
    const int wr   = w >> 1;
    const int wc   = w & 1;
    const int row0 = blockIdx.x * 128;
    const int col0 = blockIdx.y * 128;

    f32x4 acc[4][4];
#pragma unroll
    for (int i = 0; i < 4; ++i)
#pragma unroll
        for (int j = 0; j < 4; ++j) acc[i][j] = (f32x4){0.f, 0.f, 0.f, 0.f};

    const int lrow = (lane >> 3);
    const int cdst = (lane & 7) * 16;

    for (int kc = 0; kc < K; kc += 64) {
        if (kc) __syncthreads();
#pragma unroll
        for (int it = 0; it < 4; ++it) {
            int slot = it * 4 + w;
            int row  = slot * 8 + lrow;
            int csrc = cdst ^ ((row & 7) << 4);
            int ga   = row0 + row; if (ga >= M) ga = M - 1;
            gload_lds16((const char*)A + ((size_t)ga * K + kc) * 2 + csrc,
                        As + slot * 1024);
            int gw_  = col0 + row;
            gload_lds16((const char*)W + ((size_t)gw_ * K + kc) * 2 + csrc,
                        Ws + slot * 1024);
        }
        asm volatile("s_waitcnt vmcnt(0)" ::: "memory");
        __syncthreads();

#pragma unroll
        for (int ks = 0; ks < 2; ++ks) {
            short8 af[4], bf[4];
#pragma unroll
            for (int mi = 0; mi < 4; ++mi) {
                int row = wr * 64 + mi * 16 + r;
                int byte = row * 128 + ks * 64 + g * 16;
                byte ^= (r & 7) << 4;
                af[mi] = *(const short8*)(As + byte);
            }
#pragma unroll
            for (int nj = 0; nj < 4; ++nj) {
                int col = wc * 64 + nj * 16 + r;
                int byte = col * 128 + ks * 64 + g * 16;
                byte ^= (r & 7) << 4;
                bf[nj] = *(const short8*)(Ws + byte);
            }
#pragma unroll
            for (int mi = 0; mi < 4; ++mi)
#pragma unroll
                for (int nj = 0; nj < 4; ++nj)
                    acc[mi][nj] = __builtin_amdgcn_mfma_f32_16x16x32_bf16(
                        af[mi], bf[nj], acc[mi][nj], 0, 0, 0);
        }
    }

#pragma unroll
    for (int nj = 0; nj < 4; ++nj) {
        int gcol = col0 + wc * 64 + nj * 16 + r;
        float b = bias ? bias[gcol] : 0.f;
#pragma unroll
        for (int mi = 0; mi < 4; ++mi) {
#pragma unroll
            for (int q = 0; q < 4; ++q) {
                int grow = row0 + wr * 64 + mi * 16 + g * 4 + q;
                if (grow < M) {
                    float x = acc[mi][nj][q] + b;
                    if (ACT) x = silu(x);
                    C[(size_t)grow * OUT + gcol] = f32_to_bf16(x);
                }
            }
        }
    }
}

// ---------- per-graph sum: 4 deterministic partials + combine ----------
__global__ __launch_bounds__(256) void graph_partial_kernel(
        const unsigned short* __restrict__ h, const int* __restrict__ gids,
        float* __restrict__ partial, int M) {
    int gph = blockIdx.x, s = blockIdx.y;
    int c = threadIdx.x;
    int lo = 0, hi = M;
    while (lo < hi) { int mid = (lo + hi) >> 1; if (gids[mid] < gph) lo = mid + 1; else hi = mid; }
    int lo2 = lo, hi2 = M;
    while (lo2 < hi2) { int mid = (lo2 + hi2) >> 1; if (gids[mid] < gph + 1) lo2 = mid + 1; else hi2 = mid; }
    int len = lo2 - lo;
    int q = (len + 3) >> 2;
    int b0 = lo + s * q;
    int b1 = b0 + q; if (b1 > lo2) b1 = lo2;
    float a0 = 0.f, a1 = 0.f;
    int n = b0;
    for (; n + 1 < b1; n += 2) {
        a0 += bf16_to_f32(h[(size_t)n * OUT + c]);
        a1 += bf16_to_f32(h[(size_t)(n + 1) * OUT + c]);
    }
    for (; n < b1; ++n) a0 += bf16_to_f32(h[(size_t)n * OUT + c]);
    partial[((size_t)gph * 4 + s) * OUT + c] = a0 + a1;
}

__global__ __launch_bounds__(256) void graph_final_kernel(
        const float* __restrict__ partial, float* __restrict__ out) {
    int gph = blockIdx.x, c = threadIdx.x;
    const float* p = partial + (size_t)gph * 4 * OUT + c;
    out[(size_t)gph * OUT + c] = (p[0] + p[OUT]) + (p[2 * OUT] + p[3 * OUT]);
}

// ---------- host ----------
extern "C" void kernel_launch(void* const* d_in, const int* in_sizes, int n_in,
                              void* d_out, int out_size, void* d_ws, size_t ws_size,
                              hipStream_t stream) {
    const float* m         = (const float*)d_in[0];
    const float* rbf       = (const float*)d_in[1];
    const int*   src       = (const int*)d_in[2];
    const int*   gids      = (const int*)d_in[3];
    const float* W_rbf     = (const float*)d_in[4];
    const float* W_up      = (const float*)d_in[5];
    const float* W_dense   = (const float*)d_in[6];
    const float* b_dense   = (const float*)d_in[7];
    float* out = (float*)d_out;

    const int E = in_sizes[2];
    const int N = in_sizes[3];
    const int G = out_size / OUT;

    size_t off = 0;
    auto alloc = [&](size_t bytes) -> void* {
        void* p = (char*)d_ws + off;
        off += (bytes + 255) & ~(size_t)255;
        return p;
    };
    int* counts  = (int*)alloc((size_t)N * 4);
    int* offsets = (int*)alloc(((size_t)N + 1) * 4);
    int* eidx    = (int*)alloc((size_t)E * 4);
    int* perm    = (int*)alloc((size_t)E * 4);
    int* bsum    = (int*)alloc(SCAN_NB * 4);
    int* bpre    = (int*)alloc(SCAN_NB * 4);
    unsigned short* t_bf = (unsigned short*)alloc((size_t)N * EMB * 2);
    unsigned short* h0   = (unsigned short*)alloc((size_t)N * OUT * 2);
    unsigned short* h1   = (unsigned short*)alloc((size_t)N * OUT * 2);
    float* partial       = (float*)alloc((size_t)G * 4 * OUT * 4);
    unsigned short* Wbf  = (unsigned short*)alloc((size_t)(OUT * EMB + NDENSE * OUT * OUT) * 2);
    unsigned short* Wup_bf = Wbf;
    unsigned short* Wd_bf  = Wbf + OUT * EMB;

    const int chunk = (N + SCAN_NB - 1) / SCAN_NB;

    // K0: init (zero counts + weight convert)
    init_kernel<<<512, 256, 0, stream>>>(counts, W_up, W_dense, Wbf, N);

    // CSR build (1 atomic pass)
    hist_kernel<<<1024, 256, 0, stream>>>(src, counts, eidx, E);
    scanA_kernel<<<SCAN_NB, 256, 0, stream>>>(counts, bsum, N, chunk);
    scanB_kernel<<<1, 256, 0, stream>>>(bsum, bpre, offsets, N);
    scanC_kernel<<<SCAN_NB, 256, 0, stream>>>(counts, bpre, offsets, N, chunk);
    scatter_kernel<<<1024, 256, 0, stream>>>(src, offsets, eidx, perm, E);

    // edge transform + node gather v2 (2 rows / instr, 8-edge chunks)
    edge_accum_kernel<<<2048, 256, 0, stream>>>(m, rbf, perm, offsets, W_rbf,
                                                (uint2*)t_bf, N);

    // MLP as 4 GEMMs (128x128 tile, LDS-staged, 4x4 outer product)
    dim3 ggrid((N + 127) / 128, 2);
    gemm2_kernel<EMB, 0><<<ggrid, 256, 0, stream>>>(t_bf, Wup_bf, nullptr, h0, N);
    gemm2_kernel<OUT, 1><<<ggrid, 256, 0, stream>>>(h0, Wd_bf + 0 * OUT * OUT, b_dense + 0 * OUT, h1, N);
    gemm2_kernel<OUT, 1><<<ggrid, 256, 0, stream>>>(h1, Wd_bf + 1 * OUT * OUT, b_dense + 1 * OUT, h0, N);
    gemm2_kernel<OUT, 1><<<ggrid, 256, 0, stream>>>(h0, Wd_bf + 2 * OUT * OUT, b_dense + 2 * OUT, h1, N);

    // per-graph readout
    graph_partial_kernel<<<dim3(G, 4), 256, 0, stream>>>(h1, gids, partial, N);
    graph_final_kernel<<<G, 256, 0, stream>>>(partial, out);
}

// Round 10
// 477.498 us; speedup vs baseline: 7.1149x; 1.0901x over previous
//
#include <hip/hip_runtime.h>
#include <hip/hip_bf16.h>

// ---------- types ----------
typedef __attribute__((ext_vector_type(8))) short short8;
typedef __attribute__((ext_vector_type(4))) float f32x4;

#define EMB 128
#define OUT 256
#define NRAD 6
#define NDENSE 3
#define BSH 7                 // bucket shift: 128 nodes per bucket
#define MAXBKT 512            // >= ceil(N/128)

static __device__ __forceinline__ unsigned short f32_to_bf16(float f) {
    union { float f; unsigned u; } v; v.f = f;
    unsigned r = v.u + 0x7fffu + ((v.u >> 16) & 1u);   // round-nearest-even
    return (unsigned short)(r >> 16);
}
static __device__ __forceinline__ float bf16_to_f32(unsigned short h) {
    union { unsigned u; float f; } v; v.u = ((unsigned)h) << 16;
    return v.f;
}
static __device__ __forceinline__ float silu(float x) {
    return x / (1.f + __expf(-x));
}
static __device__ __forceinline__ void gload_lds16(const void* gp, void* lp) {
    __builtin_amdgcn_global_load_lds(
        (const __attribute__((address_space(1))) void*)gp,
        (__attribute__((address_space(3))) void*)lp, 16, 0, 0);
}

// ---------- K0: init (zero bucket counts + convert weights) ----------
__global__ __launch_bounds__(256) void init_kernel(
        int* __restrict__ bcnt, const float* __restrict__ Wup,
        const float* __restrict__ Wd, unsigned short* __restrict__ Wbf, int nbkt) {
    int i = blockIdx.x * blockDim.x + threadIdx.x;
    int stride = gridDim.x * blockDim.x;
    for (int j = i; j < nbkt; j += stride) bcnt[j] = 0;
    const int n1 = OUT * EMB, n2 = NDENSE * OUT * OUT;
    for (int j = i; j < n1 + n2; j += stride)
        Wbf[j] = f32_to_bf16(j < n1 ? Wup[j] : Wd[j - n1]);
}

// ---------- K1: bucket histogram (LDS pre-aggregated) ----------
__global__ __launch_bounds__(256) void bhist_kernel(
        const int* __restrict__ src, int* __restrict__ bcnt, int E, int nbkt) {
    __shared__ int h[MAXBKT];
    for (int b = threadIdx.x; b < nbkt; b += 256) h[b] = 0;
    __syncthreads();
    int stride = gridDim.x * blockDim.x;
    for (int e = blockIdx.x * blockDim.x + threadIdx.x; e < E; e += stride)
        atomicAdd(&h[src[e] >> BSH], 1);
    __syncthreads();
    for (int b = threadIdx.x; b < nbkt; b += 256)
        if (h[b]) atomicAdd(&bcnt[b], h[b]);
}

// ---------- K2: scan bucket counts -> bbase[nbkt+1], gcursor ----------
__global__ __launch_bounds__(512) void bscan_kernel(
        const int* __restrict__ bcnt, int* __restrict__ bbase,
        int* __restrict__ gcursor, int nbkt, int E) {
    __shared__ int s[MAXBKT];
    int t = threadIdx.x;
    int v = (t < nbkt) ? bcnt[t] : 0;
    s[t] = v;
    __syncthreads();
    for (int d = 1; d < MAXBKT; d <<= 1) {
        int x = (t >= d) ? s[t - d] : 0;
        __syncthreads();
        s[t] += x;
        __syncthreads();
    }
    if (t < nbkt) {
        int ex = s[t] - v;
        bbase[t] = ex;
        gcursor[t] = ex;
    }
    if (t == 0) bbase[nbkt] = E;
}

// ---------- K3: scatter edges into bucket-grouped pairs (e, src) ----------
__global__ __launch_bounds__(256) void bscatter_kernel(
        const int* __restrict__ src, int* __restrict__ gcursor,
        int2* __restrict__ pairs, int E, int nbkt) {
    __shared__ int h[MAXBKT];
    __shared__ int base[MAXBKT];
    for (int b = threadIdx.x; b < nbkt; b += 256) h[b] = 0;
    __syncthreads();
    const int per = (E + gridDim.x - 1) / gridDim.x;
    const int e0 = blockIdx.x * per;
    const int e1 = min(e0 + per, E);
    for (int e = e0 + threadIdx.x; e < e1; e += 256)
        atomicAdd(&h[src[e] >> BSH], 1);
    __syncthreads();
    for (int b = threadIdx.x; b < nbkt; b += 256)
        base[b] = h[b] ? atomicAdd(&gcursor[b], h[b]) : 0;
    __syncthreads();
    for (int e = e0 + threadIdx.x; e < e1; e += 256) {
        int s = src[e];
        int pos = atomicAdd(&base[s >> BSH], 1);
        pairs[pos] = make_int2(e, s);
    }
}

// ---------- K4: per-bucket local CSR (counting sort in LDS) ----------
__global__ __launch_bounds__(256) void local_csr_kernel(
        const int2* __restrict__ pairs, const int* __restrict__ bbase,
        int* __restrict__ offsets, int* __restrict__ perm, int N, int E, int nbkt) {
    __shared__ int cnt[128], exc[128], cur[128];
    const int b = blockIdx.x;
    const int t = threadIdx.x;
    const int n0 = b << BSH;
    const int nn = min(128, N - n0);         // nodes in this bucket
    const int p0 = bbase[b], p1 = bbase[b + 1];
    if (t < 128) cnt[t] = 0;
    __syncthreads();
    for (int i = p0 + t; i < p1; i += 256)
        atomicAdd(&cnt[pairs[i].y - n0], 1);
    __syncthreads();
    // exclusive scan of cnt[0..127] (Hillis-Steele on 128 lanes)
    if (t < 128) exc[t] = cnt[t];
    __syncthreads();
    for (int d = 1; d < 128; d <<= 1) {
        int x = (t >= d && t < 128) ? exc[t - d] : 0;
        __syncthreads();
        if (t < 128) exc[t] += x;
        __syncthreads();
    }
    if (t < 128) {
        int ex = exc[t] - cnt[t];
        cur[t] = ex;
        if (t < nn) offsets[n0 + t] = p0 + ex;
    }
    if (b == 0 && t == 0) offsets[N] = E;
    __syncthreads();
    for (int i = p0 + t; i < p1; i += 256) {
        int2 pr = pairs[i];
        int pos = p0 + atomicAdd(&cur[pr.y - n0], 1);
        perm[pos] = pr.x;
    }
}

// ---------- edge transform + per-node gather-sum v2 (IDENTICAL to R9) ----------
__global__ __launch_bounds__(256) void edge_accum_kernel(
        const float* __restrict__ m, const float* __restrict__ rbf,
        const int* __restrict__ perm, const int* __restrict__ offsets,
        const float* __restrict__ W_rbf, uint2* __restrict__ t_pack, int N) {
    const int lane = threadIdx.x & 63;
    const int h = lane >> 5;
    const int c = lane & 31;
    const int gw = blockIdx.x * (blockDim.x >> 6) + (threadIdx.x >> 6);
    const int nwaves = gridDim.x * (blockDim.x >> 6);

    float wk[4][6];
#pragma unroll
    for (int k = 0; k < 4; ++k)
#pragma unroll
        for (int j = 0; j < 6; ++j) wk[k][j] = W_rbf[(4 * c + k) * NRAD + j];

    for (int node = gw; node < N; node += nwaves) {
        const int beg = offsets[node], end = offsets[node + 1];
        float a0 = 0.f, a1 = 0.f, a2 = 0.f, a3 = 0.f;
        int pe = 0;
        if (beg < end) {
            int pi = beg + (lane & 7); if (pi > end - 1) pi = end - 1;
            pe = perm[pi];
        }
        for (int cb = beg; cb < end; cb += 8) {
            int pe_next = 0;
            if (cb + 8 < end) {
                int pi = cb + 8 + (lane & 7); if (pi > end - 1) pi = end - 1;
                pe_next = perm[pi];
            }
#pragma unroll
            for (int p = 0; p < 4; ++p) {
                int e = __shfl(pe, 2 * p + h);
                const float2* rp = (const float2*)(rbf + (size_t)e * NRAD);
                float2 r0 = rp[0], r1 = rp[1], r2 = rp[2];
                float4 mv = *(const float4*)(m + (size_t)e * EMB + 4 * c);
                float g = (cb + 2 * p + h < end) ? 1.f : 0.f;
                float p0 = (wk[0][0]*r0.x + wk[0][1]*r0.y + wk[0][2]*r1.x
                          + wk[0][3]*r1.y + wk[0][4]*r2.x + wk[0][5]*r2.y) * g;
                float p1 = (wk[1][0]*r0.x + wk[1][1]*r0.y + wk[1][2]*r1.x
                          + wk[1][3]*r1.y + wk[1][4]*r2.x + wk[1][5]*r2.y) * g;
                float p2 = (wk[2][0]*r0.x + wk[2][1]*r0.y + wk[2][2]*r1.x
                          + wk[2][3]*r1.y + wk[2][4]*r2.x + wk[2][5]*r2.y) * g;
                float p3 = (wk[3][0]*r0.x + wk[3][1]*r0.y + wk[3][2]*r1.x
                          + wk[3][3]*r1.y + wk[3][4]*r2.x + wk[3][5]*r2.y) * g;
                a0 = fmaf(mv.x, p0, a0);
                a1 = fmaf(mv.y, p1, a1);
                a2 = fmaf(mv.z, p2, a2);
                a3 = fmaf(mv.w, p3, a3);
            }
            pe = pe_next;
        }
        a0 += __shfl_xor(a0, 32);
        a1 += __shfl_xor(a1, 32);
        a2 += __shfl_xor(a2, 32);
        a3 += __shfl_xor(a3, 32);
        if (h == 0) {
            uint2 pk;
            pk.x = (unsigned)f32_to_bf16(a0) | ((unsigned)f32_to_bf16(a1) << 16);
            pk.y = (unsigned)f32_to_bf16(a2) | ((unsigned)f32_to_bf16(a3) << 16);
            t_pack[(size_t)node * 32 + c] = pk;
        }
    }
}

// ---------- GEMM (m97-style, IDENTICAL to R9) ----------
template<int K, int ACT>
__global__ __launch_bounds__(256) void gemm2_kernel(
        const unsigned short* __restrict__ A, const unsigned short* __restrict__ W,
        const float* __restrict__ bias, unsigned short* __restrict__ C, int M) {
    __shared__ char lds[32768];
    char* As = lds;
    char* Ws = lds + 16384;

    const int w    = threadIdx.x >> 6;
    const int lane = threadIdx.x & 63;
    const int r    = lane & 15;
    const int g    = lane >> 4;
    const int wr   = w >> 1;
    const int wc   = w & 1;
    const int row0 = blockIdx.x * 128;
    const int col0 = blockIdx.y * 128;

    f32x4 acc[4][4];
#pragma unroll
    for (int i = 0; i < 4; ++i)
#pragma unroll
        for (int j = 0; j < 4; ++j) acc[i][j] = (f32x4){0.f, 0.f, 0.f, 0.f};

    const int lrow = (lane >> 3);
    const int cdst = (lane & 7) * 16;

    for (int kc = 0; kc < K; kc += 64) {
        if (kc) __syncthreads();
#pragma unroll
        for (int it = 0; it < 4; ++it) {
            int slot = it * 4 + w;
            int row  = slot * 8 + lrow;
            int csrc = cdst ^ ((row & 7) << 4);
            int ga   = row0 + row; if (ga >= M) ga = M - 1;
            gload_lds16((const char*)A + ((size_t)ga * K + kc) * 2 + csrc,
                        As + slot * 1024);
            int gw_  = col0 + row;
            gload_lds16((const char*)W + ((size_t)gw_ * K + kc) * 2 + csrc,
                        Ws + slot * 1024);
        }
        asm volatile("s_waitcnt vmcnt(0)" ::: "memory");
        __syncthreads();

#pragma unroll
        for (int ks = 0; ks < 2; ++ks) {
            short8 af[4], bf[4];
#pragma unroll
            for (int mi = 0; mi < 4; ++mi) {
                int row = wr * 64 + mi * 16 + r;
                int byte = row * 128 + ks * 64 + g * 16;
                byte ^= (r & 7) << 4;
                af[mi] = *(const short8*)(As + byte);
            }
#pragma unroll
            for (int nj = 0; nj < 4; ++nj) {
                int col = wc * 64 + nj * 16 + r;
                int byte = col * 128 + ks * 64 + g * 16;
                byte ^= (r & 7) << 4;
                bf[nj] = *(const short8*)(Ws + byte);
            }
#pragma unroll
            for (int mi = 0; mi < 4; ++mi)
#pragma unroll
                for (int nj = 0; nj < 4; ++nj)
                    acc[mi][nj] = __builtin_amdgcn_mfma_f32_16x16x32_bf16(
                        af[mi], bf[nj], acc[mi][nj], 0, 0, 0);
        }
    }

#pragma unroll
    for (int nj = 0; nj < 4; ++nj) {
        int gcol = col0 + wc * 64 + nj * 16 + r;
        float b = bias ? bias[gcol] : 0.f;
#pragma unroll
        for (int mi = 0; mi < 4; ++mi) {
#pragma unroll
            for (int q = 0; q < 4; ++q) {
                int grow = row0 + wr * 64 + mi * 16 + g * 4 + q;
                if (grow < M) {
                    float x = acc[mi][nj][q] + b;
                    if (ACT) x = silu(x);
                    C[(size_t)grow * OUT + gcol] = f32_to_bf16(x);
                }
            }
        }
    }
}

// ---------- per-graph sum (IDENTICAL to R9) ----------
__global__ __launch_bounds__(256) void graph_partial_kernel(
        const unsigned short* __restrict__ h, const int* __restrict__ gids,
        float* __restrict__ partial, int M) {
    int gph = blockIdx.x, s = blockIdx.y;
    int c = threadIdx.x;
    int lo = 0, hi = M;
    while (lo < hi) { int mid = (lo + hi) >> 1; if (gids[mid] < gph) lo = mid + 1; else hi = mid; }
    int lo2 = lo, hi2 = M;
    while (lo2 < hi2) { int mid = (lo2 + hi2) >> 1; if (gids[mid] < gph + 1) lo2 = mid + 1; else hi2 = mid; }
    int len = lo2 - lo;
    int q = (len + 3) >> 2;
    int b0 = lo + s * q;
    int b1 = b0 + q; if (b1 > lo2) b1 = lo2;
    float a0 = 0.f, a1 = 0.f;
    int n = b0;
    for (; n + 1 < b1; n += 2) {
        a0 += bf16_to_f32(h[(size_t)n * OUT + c]);
        a1 += bf16_to_f32(h[(size_t)(n + 1) * OUT + c]);
    }
    for (; n < b1; ++n) a0 += bf16_to_f32(h[(size_t)n * OUT + c]);
    partial[((size_t)gph * 4 + s) * OUT + c] = a0 + a1;
}

__global__ __launch_bounds__(256) void graph_final_kernel(
        const float* __restrict__ partial, float* __restrict__ out) {
    int gph = blockIdx.x, c = threadIdx.x;
    const float* p = partial + (size_t)gph * 4 * OUT + c;
    out[(size_t)gph * OUT + c] = (p[0] + p[OUT]) + (p[2 * OUT] + p[3 * OUT]);
}

// ---------- host ----------
extern "C" void kernel_launch(void* const* d_in, const int* in_sizes, int n_in,
                              void* d_out, int out_size, void* d_ws, size_t ws_size,
                              hipStream_t stream) {
    const float* m         = (const float*)d_in[0];
    const float* rbf       = (const float*)d_in[1];
    const int*   src       = (const int*)d_in[2];
    const int*   gids      = (const int*)d_in[3];
    const float* W_rbf     = (const float*)d_in[4];
    const float* W_up      = (const float*)d_in[5];
    const float* W_dense   = (const float*)d_in[6];
    const float* b_dense   = (const float*)d_in[7];
    float* out = (float*)d_out;

    const int E = in_sizes[2];
    const int N = in_sizes[3];
    const int G = out_size / OUT;
    const int nbkt = (N + 127) >> BSH;     // 391 for N=50000

    size_t off = 0;
    auto alloc = [&](size_t bytes) -> void* {
        void* p = (char*)d_ws + off;
        off += (bytes + 255) & ~(size_t)255;
        return p;
    };
    int* bcnt    = (int*)alloc((size_t)MAXBKT * 4);
    int* bbase   = (int*)alloc((size_t)(MAXBKT + 1) * 4);
    int* gcursor = (int*)alloc((size_t)MAXBKT * 4);
    int* offsets = (int*)alloc(((size_t)N + 1) * 4);
    int2* pairs  = (int2*)alloc((size_t)E * 8);
    int* perm    = (int*)alloc((size_t)E * 4);
    unsigned short* t_bf = (unsigned short*)alloc((size_t)N * EMB * 2);
    unsigned short* h0   = (unsigned short*)alloc((size_t)N * OUT * 2);
    unsigned short* h1   = (unsigned short*)alloc((size_t)N * OUT * 2);
    float* partial       = (float*)alloc((size_t)G * 4 * OUT * 4);
    unsigned short* Wbf  = (unsigned short*)alloc((size_t)(OUT * EMB + NDENSE * OUT * OUT) * 2);
    unsigned short* Wup_bf = Wbf;
    unsigned short* Wd_bf  = Wbf + OUT * EMB;

    // K0: init (zero bucket counts + weight convert)
    init_kernel<<<512, 256, 0, stream>>>(bcnt, W_up, W_dense, Wbf, nbkt);

    // bucketed CSR build
    bhist_kernel<<<256, 256, 0, stream>>>(src, bcnt, E, nbkt);
    bscan_kernel<<<1, MAXBKT, 0, stream>>>(bcnt, bbase, gcursor, nbkt, E);
    bscatter_kernel<<<512, 256, 0, stream>>>(src, gcursor, pairs, E, nbkt);
    local_csr_kernel<<<nbkt, 256, 0, stream>>>(pairs, bbase, offsets, perm, N, E, nbkt);

    // edge transform + node gather v2
    edge_accum_kernel<<<2048, 256, 0, stream>>>(m, rbf, perm, offsets, W_rbf,
                                                (uint2*)t_bf, N);

    // MLP as 4 GEMMs
    dim3 ggrid((N + 127) / 128, 2);
    gemm2_kernel<EMB, 0><<<ggrid, 256, 0, stream>>>(t_bf, Wup_bf, nullptr, h0, N);
    gemm2_kernel<OUT, 1><<<ggrid, 256, 0, stream>>>(h0, Wd_bf + 0 * OUT * OUT, b_dense + 0 * OUT, h1, N);
    gemm2_kernel<OUT, 1><<<ggrid, 256, 0, stream>>>(h1, Wd_bf + 1 * OUT * OUT, b_dense + 1 * OUT, h0, N);
    gemm2_kernel<OUT, 1><<<ggrid, 256, 0, stream>>>(h0, Wd_bf + 2 * OUT * OUT, b_dense + 2 * OUT, h1, N);

    // per-graph readout
    graph_partial_kernel<<<dim3(G, 4), 256, 0, stream>>>(h1, gids, partial, N);
    graph_final_kernel<<<G, 256, 0, stream>>>(partial, out);
}

// Round 11
// 450.773 us; speedup vs baseline: 7.5367x; 1.0593x over previous
//
#include <hip/hip_runtime.h>
#include <hip/hip_bf16.h>

// ---------- types ----------
typedef __attribute__((ext_vector_type(8))) short short8;
typedef __attribute__((ext_vector_type(4))) float f32x4;

#define EMB 128
#define OUT 256
#define NRAD 6
#define NDENSE 3
#define BSH 7                 // bucket shift: 128 nodes per bucket
#define MAXBKT 512            // >= ceil(N/128)
#define HB 256                // bhist blocks

static __device__ __forceinline__ unsigned short f32_to_bf16(float f) {
    union { float f; unsigned u; } v; v.f = f;
    unsigned r = v.u + 0x7fffu + ((v.u >> 16) & 1u);   // round-nearest-even
    return (unsigned short)(r >> 16);
}
static __device__ __forceinline__ float bf16_to_f32(unsigned short h) {
    union { unsigned u; float f; } v; v.u = ((unsigned)h) << 16;
    return v.f;
}
static __device__ __forceinline__ float silu(float x) {
    return x / (1.f + __expf(-x));
}
static __device__ __forceinline__ void gload_lds16(const void* gp, void* lp) {
    __builtin_amdgcn_global_load_lds(
        (const __attribute__((address_space(1))) void*)gp,
        (__attribute__((address_space(3))) void*)lp, 16, 0, 0);
}

// ---------- K0: init (convert weights + zero out) ----------
__global__ __launch_bounds__(256) void init_kernel(
        const float* __restrict__ Wup, const float* __restrict__ Wd,
        unsigned short* __restrict__ Wbf, float* __restrict__ out, int outn) {
    int i = blockIdx.x * blockDim.x + threadIdx.x;
    int stride = gridDim.x * blockDim.x;
    for (int j = i; j < outn; j += stride) out[j] = 0.f;
    const int n1 = OUT * EMB, n2 = NDENSE * OUT * OUT;
    for (int j = i; j < n1 + n2; j += stride)
        Wbf[j] = f32_to_bf16(j < n1 ? Wup[j] : Wd[j - n1]);
}

// ---------- K1: bucket histogram, atomic-free (per-block partials) ----------
__global__ __launch_bounds__(256) void bhist_kernel(
        const int* __restrict__ src, int* __restrict__ bpart, int E, int nbkt) {
    __shared__ int h[MAXBKT];
    for (int b = threadIdx.x; b < nbkt; b += 256) h[b] = 0;
    __syncthreads();
    int stride = gridDim.x * blockDim.x;
    for (int e = blockIdx.x * blockDim.x + threadIdx.x; e < E; e += stride)
        atomicAdd(&h[src[e] >> BSH], 1);
    __syncthreads();
    int* row = bpart + (size_t)blockIdx.x * MAXBKT;
    for (int b = threadIdx.x; b < nbkt; b += 256) row[b] = h[b];
}

// ---------- K2: sum partials + scan -> bbase[nbkt+1], gcursor ----------
__global__ __launch_bounds__(512) void bscan_kernel(
        const int* __restrict__ bpart, int* __restrict__ bbase,
        int* __restrict__ gcursor, int nbkt, int E) {
    __shared__ int s[MAXBKT];
    int t = threadIdx.x;
    int v = 0;
    if (t < nbkt)
        for (int k = 0; k < HB; ++k) v += bpart[(size_t)k * MAXBKT + t];
    s[t] = v;
    __syncthreads();
    for (int d = 1; d < MAXBKT; d <<= 1) {
        int x = (t >= d) ? s[t - d] : 0;
        __syncthreads();
        s[t] += x;
        __syncthreads();
    }
    if (t < nbkt) {
        int ex = s[t] - v;
        bbase[t] = ex;
        gcursor[t] = ex;
    }
    if (t == 0) bbase[nbkt] = E;
}

// ---------- K3: scatter edges into bucket-grouped pairs (e, src) ----------
__global__ __launch_bounds__(256) void bscatter_kernel(
        const int* __restrict__ src, int* __restrict__ gcursor,
        int2* __restrict__ pairs, int E, int nbkt) {
    __shared__ int h[MAXBKT];
    __shared__ int base[MAXBKT];
    for (int b = threadIdx.x; b < nbkt; b += 256) h[b] = 0;
    __syncthreads();
    const int per = (E + gridDim.x - 1) / gridDim.x;
    const int e0 = blockIdx.x * per;
    const int e1 = min(e0 + per, E);
    for (int e = e0 + threadIdx.x; e < e1; e += 256)
        atomicAdd(&h[src[e] >> BSH], 1);
    __syncthreads();
    for (int b = threadIdx.x; b < nbkt; b += 256)
        base[b] = h[b] ? atomicAdd(&gcursor[b], h[b]) : 0;
    __syncthreads();
    for (int e = e0 + threadIdx.x; e < e1; e += 256) {
        int s = src[e];
        int pos = atomicAdd(&base[s >> BSH], 1);
        pairs[pos] = make_int2(e, s);
    }
}

// ---------- K4: per-bucket local CSR (counting sort in LDS) ----------
__global__ __launch_bounds__(256) void local_csr_kernel(
        const int2* __restrict__ pairs, const int* __restrict__ bbase,
        int* __restrict__ offsets, int* __restrict__ perm, int N, int E, int nbkt) {
    __shared__ int cnt[128], exc[128], cur[128];
    const int b = blockIdx.x;
    const int t = threadIdx.x;
    const int n0 = b << BSH;
    const int nn = min(128, N - n0);
    const int p0 = bbase[b], p1 = bbase[b + 1];
    if (t < 128) cnt[t] = 0;
    __syncthreads();
    for (int i = p0 + t; i < p1; i += 256)
        atomicAdd(&cnt[pairs[i].y - n0], 1);
    __syncthreads();
    if (t < 128) exc[t] = cnt[t];
    __syncthreads();
    for (int d = 1; d < 128; d <<= 1) {
        int x = (t >= d && t < 128) ? exc[t - d] : 0;
        __syncthreads();
        if (t < 128) exc[t] += x;
        __syncthreads();
    }
    if (t < 128) {
        int ex = exc[t] - cnt[t];
        cur[t] = ex;
        if (t < nn) offsets[n0 + t] = p0 + ex;
    }
    if (b == 0 && t == 0) offsets[N] = E;
    __syncthreads();
    for (int i = p0 + t; i < p1; i += 256) {
        int2 pr = pairs[i];
        int pos = p0 + atomicAdd(&cur[pr.y - n0], 1);
        perm[pos] = pr.x;
    }
}

// ---------- edge transform + per-node gather-sum v3 (16-edge chunks) ----------
// 32 lanes per edge row: lane (c = lane&31) owns cols 4c..4c+3 (float4 m-load);
// h = lane>>5 picks edge-of-pair. 16 perm ids staged in lane&15, 8 paired
// p-iterations -> 8 m-rows in flight per wave. Perm prefetched 1 chunk ahead.
__global__ __launch_bounds__(256) void edge_accum_kernel(
        const float* __restrict__ m, const float* __restrict__ rbf,
        const int* __restrict__ perm, const int* __restrict__ offsets,
        const float* __restrict__ W_rbf, uint2* __restrict__ t_pack, int N) {
    const int lane = threadIdx.x & 63;
    const int h = lane >> 5;
    const int c = lane & 31;
    const int gw = blockIdx.x * (blockDim.x >> 6) + (threadIdx.x >> 6);
    const int nwaves = gridDim.x * (blockDim.x >> 6);

    float wk[4][6];
#pragma unroll
    for (int k = 0; k < 4; ++k)
#pragma unroll
        for (int j = 0; j < 6; ++j) wk[k][j] = W_rbf[(4 * c + k) * NRAD + j];

    for (int node = gw; node < N; node += nwaves) {
        const int beg = offsets[node], end = offsets[node + 1];
        float a0 = 0.f, a1 = 0.f, a2 = 0.f, a3 = 0.f;
        int pe = 0;
        if (beg < end) {
            int pi = beg + (lane & 15); if (pi > end - 1) pi = end - 1;
            pe = perm[pi];
        }
        for (int cb = beg; cb < end; cb += 16) {
            int pe_next = 0;
            if (cb + 16 < end) {
                int pi = cb + 16 + (lane & 15); if (pi > end - 1) pi = end - 1;
                pe_next = perm[pi];
            }
#pragma unroll
            for (int p = 0; p < 8; ++p) {
                int e = __shfl(pe, 2 * p + h);
                const float2* rp = (const float2*)(rbf + (size_t)e * NRAD);
                float2 r0 = rp[0], r1 = rp[1], r2 = rp[2];
                float4 mv = *(const float4*)(m + (size_t)e * EMB + 4 * c);
                float g = (cb + 2 * p + h < end) ? 1.f : 0.f;
                float p0 = (wk[0][0]*r0.x + wk[0][1]*r0.y + wk[0][2]*r1.x
                          + wk[0][3]*r1.y + wk[0][4]*r2.x + wk[0][5]*r2.y) * g;
                float p1 = (wk[1][0]*r0.x + wk[1][1]*r0.y + wk[1][2]*r1.x
                          + wk[1][3]*r1.y + wk[1][4]*r2.x + wk[1][5]*r2.y) * g;
                float p2 = (wk[2][0]*r0.x + wk[2][1]*r0.y + wk[2][2]*r1.x
                          + wk[2][3]*r1.y + wk[2][4]*r2.x + wk[2][5]*r2.y) * g;
                float p3 = (wk[3][0]*r0.x + wk[3][1]*r0.y + wk[3][2]*r1.x
                          + wk[3][3]*r1.y + wk[3][4]*r2.x + wk[3][5]*r2.y) * g;
                a0 = fmaf(mv.x, p0, a0);
                a1 = fmaf(mv.y, p1, a1);
                a2 = fmaf(mv.z, p2, a2);
                a3 = fmaf(mv.w, p3, a3);
            }
            pe = pe_next;
        }
        a0 += __shfl_xor(a0, 32);
        a1 += __shfl_xor(a1, 32);
        a2 += __shfl_xor(a2, 32);
        a3 += __shfl_xor(a3, 32);
        if (h == 0) {
            uint2 pk;
            pk.x = (unsigned)f32_to_bf16(a0) | ((unsigned)f32_to_bf16(a1) << 16);
            pk.y = (unsigned)f32_to_bf16(a2) | ((unsigned)f32_to_bf16(a3) << 16);
            t_pack[(size_t)node * 32 + c] = pk;
        }
    }
}

// ---------- GEMM (m97-style, IDENTICAL to R10) ----------
template<int K, int ACT>
__global__ __launch_bounds__(256) void gemm2_kernel(
        const unsigned short* __restrict__ A, const unsigned short* __restrict__ W,
        const float* __restrict__ bias, unsigned short* __restrict__ C, int M) {
    __shared__ char lds[32768];
    char* As = lds;
    char* Ws = lds + 16384;

    const int w    = threadIdx.x >> 6;
    const int lane = threadIdx.x & 63;
    const int r    = lane & 15;
    const int g    = lane >> 4;
    const int wr   = w >> 1;
    const int wc   = w & 1;
    const int row0 = blockIdx.x * 128;
    const int col0 = blockIdx.y * 128;

    f32x4 acc[4][4];
#pragma unroll
    for (int i = 0; i < 4; ++i)
#pragma unroll
        for (int j = 0; j < 4; ++j) acc[i][j] = (f32x4){0.f, 0.f, 0.f, 0.f};

    const int lrow = (lane >> 3);
    const int cdst = (lane & 7) * 16;

    for (int kc = 0; kc < K; kc += 64) {
        if (kc) __syncthreads();
#pragma unroll
        for (int it = 0; it < 4; ++it) {
            int slot = it * 4 + w;
            int row  = slot * 8 + lrow;
            int csrc = cdst ^ ((row & 7) << 4);
            int ga   = row0 + row; if (ga >= M) ga = M - 1;
            gload_lds16((const char*)A + ((size_t)ga * K + kc) * 2 + csrc,
                        As + slot * 1024);
            int gw_  = col0 + row;
            gload_lds16((const char*)W + ((size_t)gw_ * K + kc) * 2 + csrc,
                        Ws + slot * 1024);
        }
        asm volatile("s_waitcnt vmcnt(0)" ::: "memory");
        __syncthreads();

#pragma unroll
        for (int ks = 0; ks < 2; ++ks) {
            short8 af[4], bf[4];
#pragma unroll
            for (int mi = 0; mi < 4; ++mi) {
                int row = wr * 64 + mi * 16 + r;
                int byte = row * 128 + ks * 64 + g * 16;
                byte ^= (r & 7) << 4;
                af[mi] = *(const short8*)(As + byte);
            }
#pragma unroll
            for (int nj = 0; nj < 4; ++nj) {
                int col = wc * 64 + nj * 16 + r;
                int byte = col * 128 + ks * 64 + g * 16;
                byte ^= (r & 7) << 4;
                bf[nj] = *(const short8*)(Ws + byte);
            }
#pragma unroll
            for (int mi = 0; mi < 4; ++mi)
#pragma unroll
                for (int nj = 0; nj < 4; ++nj)
                    acc[mi][nj] = __builtin_amdgcn_mfma_f32_16x16x32_bf16(
                        af[mi], bf[nj], acc[mi][nj], 0, 0, 0);
        }
    }

#pragma unroll
    for (int nj = 0; nj < 4; ++nj) {
        int gcol = col0 + wc * 64 + nj * 16 + r;
        float b = bias ? bias[gcol] : 0.f;
#pragma unroll
        for (int mi = 0; mi < 4; ++mi) {
#pragma unroll
            for (int q = 0; q < 4; ++q) {
                int grow = row0 + wr * 64 + mi * 16 + g * 4 + q;
                if (grow < M) {
                    float x = acc[mi][nj][q] + b;
                    if (ACT) x = silu(x);
                    C[(size_t)grow * OUT + gcol] = f32_to_bf16(x);
                }
            }
        }
    }
}

// ---------- per-graph sum: 4 partials, atomicAdd into out ----------
__global__ __launch_bounds__(256) void graph_partial_kernel(
        const unsigned short* __restrict__ h, const int* __restrict__ gids,
        float* __restrict__ out, int M) {
    int gph = blockIdx.x, s = blockIdx.y;
    int c = threadIdx.x;
    int lo = 0, hi = M;
    while (lo < hi) { int mid = (lo + hi) >> 1; if (gids[mid] < gph) lo = mid + 1; else hi = mid; }
    int lo2 = lo, hi2 = M;
    while (lo2 < hi2) { int mid = (lo2 + hi2) >> 1; if (gids[mid] < gph + 1) lo2 = mid + 1; else hi2 = mid; }
    int len = lo2 - lo;
    int q = (len + 3) >> 2;
    int b0 = lo + s * q;
    int b1 = b0 + q; if (b1 > lo2) b1 = lo2;
    float a0 = 0.f, a1 = 0.f;
    int n = b0;
    for (; n + 1 < b1; n += 2) {
        a0 += bf16_to_f32(h[(size_t)n * OUT + c]);
        a1 += bf16_to_f32(h[(size_t)(n + 1) * OUT + c]);
    }
    for (; n < b1; ++n) a0 += bf16_to_f32(h[(size_t)n * OUT + c]);
    float v = a0 + a1;
    if (b0 < b1) atomicAdd(&out[(size_t)gph * OUT + c], v);
}

// ---------- host ----------
extern "C" void kernel_launch(void* const* d_in, const int* in_sizes, int n_in,
                              void* d_out, int out_size, void* d_ws, size_t ws_size,
                              hipStream_t stream) {
    const float* m         = (const float*)d_in[0];
    const float* rbf       = (const float*)d_in[1];
    const int*   src       = (const int*)d_in[2];
    const int*   gids      = (const int*)d_in[3];
    const float* W_rbf     = (const float*)d_in[4];
    const float* W_up      = (const float*)d_in[5];
    const float* W_dense   = (const float*)d_in[6];
    const float* b_dense   = (const float*)d_in[7];
    float* out = (float*)d_out;

    const int E = in_sizes[2];
    const int N = in_sizes[3];
    const int G = out_size / OUT;
    const int nbkt = (N + 127) >> BSH;     // 391 for N=50000

    size_t off = 0;
    auto alloc = [&](size_t bytes) -> void* {
        void* p = (char*)d_ws + off;
        off += (bytes + 255) & ~(size_t)255;
        return p;
    };
    int* bpart   = (int*)alloc((size_t)HB * MAXBKT * 4);
    int* bbase   = (int*)alloc((size_t)(MAXBKT + 1) * 4);
    int* gcursor = (int*)alloc((size_t)MAXBKT * 4);
    int* offsets = (int*)alloc(((size_t)N + 1) * 4);
    int2* pairs  = (int2*)alloc((size_t)E * 8);
    int* perm    = (int*)alloc((size_t)E * 4);
    unsigned short* t_bf = (unsigned short*)alloc((size_t)N * EMB * 2);
    unsigned short* h0   = (unsigned short*)alloc((size_t)N * OUT * 2);
    unsigned short* h1   = (unsigned short*)alloc((size_t)N * OUT * 2);
    unsigned short* Wbf  = (unsigned short*)alloc((size_t)(OUT * EMB + NDENSE * OUT * OUT) * 2);
    unsigned short* Wup_bf = Wbf;
    unsigned short* Wd_bf  = Wbf + OUT * EMB;

    // K1: bucket histogram (no deps, atomic-free partials)
    bhist_kernel<<<HB, 256, 0, stream>>>(src, bpart, E, nbkt);
    // K0: init (weights + out zero) — independent, overlaps in graph
    init_kernel<<<512, 256, 0, stream>>>(W_up, W_dense, Wbf, out, out_size);
    // K2..K4: scan, scatter, local CSR
    bscan_kernel<<<1, MAXBKT, 0, stream>>>(bpart, bbase, gcursor, nbkt, E);
    bscatter_kernel<<<512, 256, 0, stream>>>(src, gcursor, pairs, E, nbkt);
    local_csr_kernel<<<nbkt, 256, 0, stream>>>(pairs, bbase, offsets, perm, N, E, nbkt);

    // edge transform + node gather v3 (16-edge chunks)
    edge_accum_kernel<<<2048, 256, 0, stream>>>(m, rbf, perm, offsets, W_rbf,
                                                (uint2*)t_bf, N);

    // MLP as 4 GEMMs
    dim3 ggrid((N + 127) / 128, 2);
    gemm2_kernel<EMB, 0><<<ggrid, 256, 0, stream>>>(t_bf, Wup_bf, nullptr, h0, N);
    gemm2_kernel<OUT, 1><<<ggrid, 256, 0, stream>>>(h0, Wd_bf + 0 * OUT * OUT, b_dense + 0 * OUT, h1, N);
    gemm2_kernel<OUT, 1><<<ggrid, 256, 0, stream>>>(h1, Wd_bf + 1 * OUT * OUT, b_dense + 1 * OUT, h0, N);
    gemm2_kernel<OUT, 1><<<ggrid, 256, 0, stream>>>(h0, Wd_bf + 2 * OUT * OUT, b_dense + 2 * OUT, h1, N);

    // per-graph readout (atomic into zeroed out)
    graph_partial_kernel<<<dim3(G, 4), 256, 0, stream>>>(h1, gids, out, N);
}